// Round 7
// baseline (144.916 us; speedup 1.0000x reference)
//
#include <hip/hip_runtime.h>

// QLSTM: T=64, B=256, D=512, NQ=6.
// Closed form for _qlayer: with C_w = cos(x_w + theta_w):
//   z0 = C1*C2*C3*C4*C5, z1 = C0*C1, z2 = C0*C1*C2, z3 = C0..C3, z4 = C0..C4, z5 = C0..C5
//
// gemm_pre: k across lanes, 8 rows per wave (R7: was 4 -> halves LDS-pipe
//   traffic per FMA; 256 blocks = 1/CU, 8 waves, 2/SIMD at <=256 VGPR).
//   - lane l covers k = {l, 64+l, ...}; A reads coalesced global dwords,
//     next-chunk register prefetch, no barriers in k-loop.
//   - W staged once per block into LDS [k][26]; 12 ds_read_b64 per 192 FMAs.
//   - reduction: quad DPP adds, static register indexing ONLY (R4 lesson:
//     dynamic reg indexing -> scratch spill, 845 MB traffic).
//   - epilogue: two-pass LDS overlay (waves 0-3 then 4-7; 4 waves x 192 vals
//     x 16 quads = 12288 floats <= 13312 W region).
// qlstm_scan: 4 threads/batch (one per gate, one hw quad per batch);
//   gate exchange via mov_dpp quad_perm; 2-deep prefetch of pre;
//   h@Wh in v_pk_fma_f32 (R7: 36 -> 18 VALU inst).

typedef float v2f __attribute__((ext_vector_type(2)));

__device__ __forceinline__ float fast_rcp(float x) { return __builtin_amdgcn_rcpf(x); }

template <int CTRL>
__device__ __forceinline__ float dpp_add(float x) {
    int t = __builtin_amdgcn_mov_dpp(__float_as_int(x), CTRL, 0xF, 0xF, true);
    return x + __int_as_float(t);
}

template <int G>
__device__ __forceinline__ float quad_bcast(float v) {
    int i = __builtin_amdgcn_mov_dpp(__float_as_int(v), G * 0x55, 0xF, 0xF, true);
    return __int_as_float(i);
}

__global__ __launch_bounds__(512, 2) void gemm_pre(
    const float* __restrict__ X,
    const float* __restrict__ Wf, const float* __restrict__ bf,
    const float* __restrict__ Wi, const float* __restrict__ bi,
    const float* __restrict__ Wu, const float* __restrict__ bu,
    const float* __restrict__ Wo, const float* __restrict__ bo,
    const float* __restrict__ thf, const float* __restrict__ thi,
    const float* __restrict__ thu, const float* __restrict__ tho,
    float* __restrict__ pre)
{
    // W_lds[k*26 + g*6 + j] = Wg[k][j]; 512*26 = 13312 floats = 53 KB.
    // Epilogue overlays (per pass) red[(w4*192+v)*16+q], 12288 floats.
    __shared__ float W_lds[13312];

    const int tid  = threadIdx.x;
    const int w    = tid >> 6;          // wave 0..7
    const int lane = tid & 63;
    const int rowbase = blockIdx.x * 64;  // 8 waves * 8 rows

    // ---- stage W into LDS (once per block; iteration i == gate i) ----
    #pragma unroll
    for (int i = 0; i < 4; ++i) {
        const float* Wp = (i==0)?Wf:(i==1)?Wi:(i==2)?Wu:Wo;
        int k = tid;                    // 512 threads == 512 k rows
        const float2* s = (const float2*)(Wp + k*6);
        float2* d = (float2*)(W_lds + k*26 + i*6);
        d[0] = s[0]; d[1] = s[1]; d[2] = s[2];
    }
    __syncthreads();

    // ---- main loop: 8 chunks of 64 k, register prefetch of A ----
    v2f acc[8][12];
    #pragma unroll
    for (int r = 0; r < 8; ++r)
        #pragma unroll
        for (int p = 0; p < 12; ++p) acc[r][p] = (v2f){0.f, 0.f};

    const float* Xr0 = X + (rowbase + w*8)*512 + lane;

    float pa[8];
    #pragma unroll
    for (int r = 0; r < 8; ++r) pa[r] = Xr0[r*512];

    #pragma unroll
    for (int kb = 0; kb < 512; kb += 64) {
        const v2f* wrow = (const v2f*)(W_lds + (kb + lane)*26);
        #pragma unroll
        for (int p = 0; p < 12; ++p) {
            v2f wv = wrow[p];
            #pragma unroll
            for (int r = 0; r < 8; ++r)
                acc[r][p] = __builtin_elementwise_fma((v2f){pa[r],pa[r]}, wv, acc[r][p]);
        }
        if (kb < 448) {
            #pragma unroll
            for (int r = 0; r < 8; ++r) pa[r] = Xr0[kb + 64 + r*512];
        }
    }

    // ---- quad reduction: static indexing only ----
    #pragma unroll
    for (int r = 0; r < 8; ++r)
        #pragma unroll
        for (int p = 0; p < 12; ++p) {
            float x = acc[r][p].x;
            x = dpp_add<0xB1>(x);       // quad_perm [1,0,3,2]
            x = dpp_add<0x4E>(x);       // quad_perm [2,3,0,1]
            acc[r][p].x = x;
            float y = acc[r][p].y;
            y = dpp_add<0xB1>(y);
            y = dpp_add<0x4E>(y);
            acc[r][p].y = y;
        }

    // flat value v = r*24 + col, col = 2p + e  ->  acc[v/24][(v%24)/2].{x|y}
    #define ACCV(v) ((((v) & 1) == 0) ? acc[(v)/24][((v)%24)/2].x \
                                      : acc[(v)/24][((v)%24)/2].y)
    const int j = lane & 3;             // which of the 4 values this lane stores
    const int q = lane >> 2;            // quad index 0..15
    const bool j1 = (j & 1) != 0, j2 = (j & 2) != 0;

    __syncthreads();                    // all waves done reading W_lds

    #pragma unroll
    for (int pass = 0; pass < 2; ++pass) {
        if ((w >> 2) == pass) {
            const int w4 = w & 3;
            #pragma unroll
            for (int i = 0; i < 48; ++i) {
                float c0 = ACCV(i*4 + 0), c1 = ACCV(i*4 + 1);
                float c2 = ACCV(i*4 + 2), c3 = ACCV(i*4 + 3);
                float lo = j1 ? c1 : c0;
                float hi = j1 ? c3 : c2;
                float s  = j2 ? hi : lo;
                // addr = (w4*192 + i*4 + j)*16 + q : 2-way banks only
                W_lds[(w4*192 + i*4 + j)*16 + q] = s;
            }
        }
        __syncthreads();
        // reduce this pass's 768 outputs (waves pass*4 .. pass*4+3)
        for (int o = tid; o < 768; o += 512) {
            int wv4 = o / 192, v = o - wv4*192;
            int rr = v / 24, col = v - rr*24;
            const float4* rp = (const float4*)(W_lds + (wv4*192 + v)*16);
            float4 r0 = rp[0], r1 = rp[1], r2 = rp[2], r3 = rp[3];
            float s = ((r0.x+r0.y)+(r0.z+r0.w)) + ((r1.x+r1.y)+(r1.z+r1.w))
                    + ((r2.x+r2.y)+(r2.z+r2.w)) + ((r3.x+r3.y)+(r3.z+r3.w));
            int g = col / 6, jg = col - g*6;
            const float* bb = (g==0)?bf:(g==1)?bi:(g==2)?bu:bo;
            const float* tt = (g==0)?thf:(g==1)?thi:(g==2)?thu:tho;
            s += bb[jg] + tt[jg];
            int row = rowbase + (pass*4 + wv4)*8 + rr;
            pre[row*24 + col] = s;
        }
        __syncthreads();
    }
    #undef ACCV
}

__global__ __launch_bounds__(64, 1) void qlstm_scan(
    const float* __restrict__ pre,
    const float* __restrict__ Wf, const float* __restrict__ Wi,
    const float* __restrict__ Wu, const float* __restrict__ Wo,
    float* __restrict__ out)
{
    // 4 threads per batch element (one per gate), one aligned hw quad per batch.
    const int lane = threadIdx.x;
    const int bl   = lane >> 2;          // batch-local 0..15
    const int g    = lane & 3;           // 0=f 1=i 2=u 3=o
    const int b    = blockIdx.x * 16 + bl;

    // this gate's recurrent weights, packed as v2f pairs (rows 512..517 of Wg)
    const float* Wg = (g==0)?Wf:(g==1)?Wi:(g==2)?Wu:Wo;
    v2f Wh2[6][3];
    #pragma unroll
    for (int j = 0; j < 6; ++j)
        #pragma unroll
        for (int p = 0; p < 3; ++p)
            Wh2[j][p] = (v2f){Wg[(512 + j)*6 + 2*p], Wg[(512 + j)*6 + 2*p + 1]};

    // tanh(x) = 2*sigmoid(2x)-1 -> branchless per-gate constants
    const float k1 = (g==2) ? 2.f : 1.f;
    const float k2 = (g==2) ? 2.f : 1.f;
    const float k3 = (g==2) ? -1.f : 0.f;

    float h[6], c[6];
    #pragma unroll
    for (int w = 0; w < 6; ++w) { h[w] = 0.f; c[w] = 0.f; }

    // 2-step-deep prefetch of pre
    const float* pb = pre + b*24 + g*6;
    v2f x0 = *(const v2f*)(pb);
    v2f x1 = *(const v2f*)(pb + 2);
    v2f x2 = *(const v2f*)(pb + 4);
    v2f n0 = *(const v2f*)(pb + 256*24);
    v2f n1 = *(const v2f*)(pb + 256*24 + 2);
    v2f n2 = *(const v2f*)(pb + 256*24 + 4);

    for (int t = 0; t < 64; ++t) {
        v2f a2[3] = {x0, x1, x2};
        x0 = n0; x1 = n1; x2 = n2;
        int tn = (t < 62) ? (t + 2) : 63;   // prefetch t+2
        const float* pn = pre + (tn*256 + b)*24 + g*6;
        n0 = *(const v2f*)(pn);
        n1 = *(const v2f*)(pn + 2);
        n2 = *(const v2f*)(pn + 4);

        // a = xw + h@Wh via packed fma (18 v_pk_fma_f32)
        #pragma unroll
        for (int j = 0; j < 6; ++j) {
            v2f hj = (v2f){h[j], h[j]};
            #pragma unroll
            for (int p = 0; p < 3; ++p)
                a2[p] = __builtin_elementwise_fma(hj, Wh2[j][p], a2[p]);
        }

        float C[6];
        C[0] = __cosf(a2[0].x); C[1] = __cosf(a2[0].y);
        C[2] = __cosf(a2[1].x); C[3] = __cosf(a2[1].y);
        C[4] = __cosf(a2[2].x); C[5] = __cosf(a2[2].y);

        // tree-structured products (depth 3)
        float p01 = C[0]*C[1], p23 = C[2]*C[3], p45 = C[4]*C[5];
        float z[6];
        z[1] = p01;
        z[2] = p01*C[2];
        z[3] = p01*p23;
        z[4] = z[3]*C[4];
        z[5] = z[3]*p45;
        z[0] = C[1]*(p23*p45);

        float act[6];
        #pragma unroll
        for (int w = 0; w < 6; ++w) {
            float e = __expf(-k1 * z[w]);
            act[w] = fmaf(k2, fast_rcp(1.f + e), k3);
        }

        // quad-broadcast exchange via DPP: all four gates' act[6] to every lane
        float F[6], I[6], U[6], O[6];
        #pragma unroll
        for (int w = 0; w < 6; ++w) {
            F[w] = quad_bcast<0>(act[w]);
            I[w] = quad_bcast<1>(act[w]);
            U[w] = quad_bcast<2>(act[w]);
            O[w] = quad_bcast<3>(act[w]);
        }

        #pragma unroll
        for (int w = 0; w < 6; ++w) {
            c[w] = fmaf(F[w], c[w], I[w]*U[w]);
            float e  = __expf(-2.f * c[w]);
            float tc = fmaf(2.f, fast_rcp(1.f + e), -1.f);
            h[w] = O[w]*tc;
        }

        if (g < 3) {
            float2 v;
            v.x = (g==0) ? h[0] : (g==1) ? h[2] : h[4];
            v.y = (g==0) ? h[1] : (g==1) ? h[3] : h[5];
            *(float2*)(out + (t*256 + b)*6 + g*2) = v;
        }
    }

    if (g < 3) {
        float2 v;
        v.x = (g==0) ? h[0] : (g==1) ? h[2] : h[4];
        v.y = (g==0) ? h[1] : (g==1) ? h[3] : h[5];
        *(float2*)(out + 64*256*6 + b*6 + g*2) = v;
        float2 u;
        u.x = (g==0) ? c[0] : (g==1) ? c[2] : c[4];
        u.y = (g==0) ? c[1] : (g==1) ? c[3] : c[5];
        *(float2*)(out + 64*256*6 + 256*6 + b*6 + g*2) = u;
    }
}

extern "C" void kernel_launch(void* const* d_in, const int* in_sizes, int n_in,
                              void* d_out, int out_size, void* d_ws, size_t ws_size,
                              hipStream_t stream) {
    const float* X   = (const float*)d_in[0];
    const float* Wf  = (const float*)d_in[1];
    const float* bf_ = (const float*)d_in[2];
    const float* Wi  = (const float*)d_in[3];
    const float* bi_ = (const float*)d_in[4];
    const float* Wu  = (const float*)d_in[5];
    const float* bu_ = (const float*)d_in[6];
    const float* Wo  = (const float*)d_in[7];
    const float* bo_ = (const float*)d_in[8];
    const float* thf = (const float*)d_in[9];
    const float* thi = (const float*)d_in[10];
    const float* thu = (const float*)d_in[11];
    const float* tho = (const float*)d_in[12];

    float* pre = (float*)d_ws;           // 16384*24 floats = 1.57 MB
    float* out = (float*)d_out;

    gemm_pre<<<256, 512, 0, stream>>>(X, Wf, bf_, Wi, bi_, Wu, bu_, Wo, bo_,
                                      thf, thi, thu, tho, pre);
    qlstm_scan<<<16, 64, 0, stream>>>(pre, Wf, Wi, Wu, Wo, out);
}

// Round 8
// 139.501 us; speedup vs baseline: 1.0388x; 1.0388x over previous
//
#include <hip/hip_runtime.h>

// QLSTM: T=64, B=256, D=512, NQ=6.
// Closed form for _qlayer: with C_w = cos(x_w + theta_w):
//   z0 = C1*C2*C3*C4*C5, z1 = C0*C1, z2 = C0*C1*C2, z3 = C0..C3, z4 = C0..C4, z5 = C0..C5
//
// gemm_pre (R8): k across lanes; wave = (row-group, col-half).
//   - 512 blocks x 512 thr; block = 32 rows; wave w: rg=w>>1 (8 rows), cg=w&1
//     (12 of 24 cols) -> W LDS reads per CU halved vs R5.
//   - W staged once per block into LDS stride-25 (odd stride: lane*25 mod 32
//     covers all 32 banks -> conflict-free); pair reads (c, c+6) from one
//     base -> ds_read2_b32, 6 insts per chunk per wave.
//   - acc = 8 rows x 6 v2f pairs = 96 scalars/lane (R5-proven pressure;
//     R7's 192 regressed). Static register indexing ONLY (R4 lesson).
//   - epilogue: quad DPP reduce -> cndmask select -> LDS overlay (12288 <=
//     12800 W region) -> final cross-quad sum + bias.
// qlstm_scan (R8): 4 threads/batch (one per gate, one hw quad per batch);
//   DPP quad_perm gate exchange; 2-deep prefetch of pre; pk_fma h@Wh;
//   NO v_exp: gate z in [-1,1] -> sigmoid quintic / tanh Pade(3,2);
//   tanh(c) (|c|<~2.1) -> Pade(5,4). Only rcp on the trans pipe.

typedef float v2f __attribute__((ext_vector_type(2)));

__device__ __forceinline__ float fast_rcp(float x) { return __builtin_amdgcn_rcpf(x); }

template <int CTRL>
__device__ __forceinline__ float dpp_add(float x) {
    int t = __builtin_amdgcn_mov_dpp(__float_as_int(x), CTRL, 0xF, 0xF, true);
    return x + __int_as_float(t);
}

template <int G>
__device__ __forceinline__ float quad_bcast(float v) {
    int i = __builtin_amdgcn_mov_dpp(__float_as_int(v), G * 0x55, 0xF, 0xF, true);
    return __int_as_float(i);
}

__global__ __launch_bounds__(512, 2) void gemm_pre(
    const float* __restrict__ X,
    const float* __restrict__ Wf, const float* __restrict__ bf,
    const float* __restrict__ Wi, const float* __restrict__ bi,
    const float* __restrict__ Wu, const float* __restrict__ bu,
    const float* __restrict__ Wo, const float* __restrict__ bo,
    const float* __restrict__ thf, const float* __restrict__ thi,
    const float* __restrict__ thu, const float* __restrict__ tho,
    float* __restrict__ pre)
{
    // W_lds[k*25 + c] = col c of row k (c = g*6+j); 512*25 = 12800 floats.
    // Epilogue overlays red[(w*96+v)*16+q], 12288 floats.
    __shared__ float W_lds[12800];

    const int tid  = threadIdx.x;
    const int w    = tid >> 6;          // wave 0..7
    const int lane = tid & 63;
    const int rg   = w >> 1;            // row group 0..3 (8 rows each)
    const int cg   = w & 1;             // col half 0..1 (12 cols each)
    const int rowbase = blockIdx.x * 32;

    // ---- stage W into LDS (once per block); thread tid stages row k=tid ----
    {
        const int k = tid;
        #pragma unroll
        for (int g = 0; g < 4; ++g) {
            const float* Wp = (g==0)?Wf:(g==1)?Wi:(g==2)?Wu:Wo;
            const float2* s = (const float2*)(Wp + k*6);
            float2 s0 = s[0], s1 = s[1], s2 = s[2];
            float* d = W_lds + k*25 + g*6;
            d[0] = s0.x; d[1] = s0.y; d[2] = s1.x;
            d[3] = s1.y; d[4] = s2.x; d[5] = s2.y;
        }
    }
    __syncthreads();

    // ---- main loop: 8 chunks of 64 k, register prefetch of A ----
    v2f acc[8][6];                      // acc[r][p] = {col cg*12+p, col cg*12+p+6}
    #pragma unroll
    for (int r = 0; r < 8; ++r)
        #pragma unroll
        for (int p = 0; p < 6; ++p) acc[r][p] = (v2f){0.f, 0.f};

    const float* Xr0 = X + (rowbase + rg*8)*512 + lane;
    const int colbase = cg*12;

    float pa[8];
    #pragma unroll
    for (int r = 0; r < 8; ++r) pa[r] = Xr0[r*512];

    #pragma unroll
    for (int kb = 0; kb < 512; kb += 64) {
        const float* Wrow = W_lds + (kb + lane)*25 + colbase;
        #pragma unroll
        for (int p = 0; p < 6; ++p) {
            float wa = Wrow[p];
            float wb = Wrow[p + 6];     // merges into ds_read2_b32, conflict-free
            v2f wv = (v2f){wa, wb};
            #pragma unroll
            for (int r = 0; r < 8; ++r)
                acc[r][p] = __builtin_elementwise_fma((v2f){pa[r],pa[r]}, wv, acc[r][p]);
        }
        if (kb < 448) {
            #pragma unroll
            for (int r = 0; r < 8; ++r) pa[r] = Xr0[kb + 64 + r*512];
        }
    }

    // ---- quad reduction: static indexing only ----
    #pragma unroll
    for (int r = 0; r < 8; ++r)
        #pragma unroll
        for (int p = 0; p < 6; ++p) {
            float x = acc[r][p].x;
            x = dpp_add<0xB1>(x);       // quad_perm [1,0,3,2]
            x = dpp_add<0x4E>(x);       // quad_perm [2,3,0,1]
            acc[r][p].x = x;
            float y = acc[r][p].y;
            y = dpp_add<0xB1>(y);
            y = dpp_add<0x4E>(y);
            acc[r][p].y = y;
        }

    // flat v = r*12 + ph, ph = p + 6*e  ->  acc[v/12][v%6].{x if ph<6 else y}
    #define ACCV(v) ((((v) % 12) < 6) ? acc[(v)/12][(v)%6].x \
                                      : acc[(v)/12][(v)%6].y)
    const int j = lane & 3;             // which of the 4 values this lane stores
    const int q = lane >> 2;            // quad index 0..15
    const bool j1 = (j & 1) != 0, j2 = (j & 2) != 0;
    float sel[24];
    #pragma unroll
    for (int i = 0; i < 24; ++i) {
        float c0 = ACCV(i*4 + 0), c1 = ACCV(i*4 + 1);
        float c2 = ACCV(i*4 + 2), c3 = ACCV(i*4 + 3);
        float lo = j1 ? c1 : c0;
        float hi = j1 ? c3 : c2;
        sel[i] = j2 ? hi : lo;
    }
    #undef ACCV

    __syncthreads();                    // everyone done reading W_lds
    #pragma unroll
    for (int i = 0; i < 24; ++i) {
        // addr = (w*96 + i*4 + j)*16 + q : lanes cover 64 consecutive dwords
        W_lds[(w*96 + i*4 + j)*16 + q] = sel[i];
    }
    __syncthreads();

    // ---- final: 768 outputs per block (8 waves * 8 rows * 12 cols) ----
    for (int o = tid; o < 768; o += 512) {
        int ww = o / 96, v = o - ww*96;
        int rr = v / 12, ph = v - rr*12;
        const float4* rp = (const float4*)(W_lds + (ww*96 + v)*16);
        float4 r0 = rp[0], r1 = rp[1], r2 = rp[2], r3 = rp[3];
        float s = ((r0.x+r0.y)+(r0.z+r0.w)) + ((r1.x+r1.y)+(r1.z+r1.w))
                + ((r2.x+r2.y)+(r2.z+r2.w)) + ((r3.x+r3.y)+(r3.z+r3.w));
        int col = (ww & 1)*12 + ph;
        int g = col / 6, jg = col - g*6;
        const float* bb = (g==0)?bf:(g==1)?bi:(g==2)?bu:bo;
        const float* tt = (g==0)?thf:(g==1)?thi:(g==2)?thu:tho;
        s += bb[jg] + tt[jg];
        int row = rowbase + (ww >> 1)*8 + rr;
        pre[row*24 + col] = s;
    }
}

__global__ __launch_bounds__(64, 1) void qlstm_scan(
    const float* __restrict__ pre,
    const float* __restrict__ Wf, const float* __restrict__ Wi,
    const float* __restrict__ Wu, const float* __restrict__ Wo,
    float* __restrict__ out)
{
    // 4 threads per batch element (one per gate), one aligned hw quad per batch.
    const int lane = threadIdx.x;
    const int bl   = lane >> 2;          // batch-local 0..15
    const int g    = lane & 3;           // 0=f 1=i 2=u 3=o
    const int b    = blockIdx.x * 16 + bl;

    // this gate's recurrent weights, packed as v2f pairs (rows 512..517 of Wg)
    const float* Wg = (g==0)?Wf:(g==1)?Wi:(g==2)?Wu:Wo;
    v2f Wh2[6][3];
    #pragma unroll
    for (int j = 0; j < 6; ++j)
        #pragma unroll
        for (int p = 0; p < 3; ++p)
            Wh2[j][p] = (v2f){Wg[(512 + j)*6 + 2*p], Wg[(512 + j)*6 + 2*p + 1]};

    // act(z) = c0 + z*(n0 + n1*y + n2*y^2) * rcp(d0 + d1*y), y = z^2, z in [-1,1]
    // sigmoid (g!=2): 0.5 + z/4 - z^3/48 + z^5/480   (err <= 2.1e-4)
    // tanh    (g==2): z*(15+y)/(15+6y)  Pade(3,2)    (err <= 3e-4)
    const float c0 = (g==2) ? 0.f        : 0.5f;
    const float n0 = (g==2) ? 15.f       : 0.25f;
    const float n1 = (g==2) ? 1.f        : -0.020833333f;
    const float n2 = (g==2) ? 0.f        : 0.0020833333f;
    const float d0 = (g==2) ? 15.f       : 1.f;
    const float d1 = (g==2) ? 6.f        : 0.f;

    float h[6], c[6];
    #pragma unroll
    for (int w = 0; w < 6; ++w) { h[w] = 0.f; c[w] = 0.f; }

    // 2-step-deep prefetch of pre
    const float* pb = pre + b*24 + g*6;
    v2f x0 = *(const v2f*)(pb);
    v2f x1 = *(const v2f*)(pb + 2);
    v2f x2 = *(const v2f*)(pb + 4);
    v2f n0v = *(const v2f*)(pb + 256*24);
    v2f n1v = *(const v2f*)(pb + 256*24 + 2);
    v2f n2v = *(const v2f*)(pb + 256*24 + 4);

    for (int t = 0; t < 64; ++t) {
        v2f a2[3] = {x0, x1, x2};
        x0 = n0v; x1 = n1v; x2 = n2v;
        int tn = (t < 62) ? (t + 2) : 63;   // prefetch t+2
        const float* pn = pre + (tn*256 + b)*24 + g*6;
        n0v = *(const v2f*)(pn);
        n1v = *(const v2f*)(pn + 2);
        n2v = *(const v2f*)(pn + 4);

        // a = xw + h@Wh via packed fma (18 v_pk_fma_f32)
        #pragma unroll
        for (int j = 0; j < 6; ++j) {
            v2f hj = (v2f){h[j], h[j]};
            #pragma unroll
            for (int p = 0; p < 3; ++p)
                a2[p] = __builtin_elementwise_fma(hj, Wh2[j][p], a2[p]);
        }

        float C[6];
        C[0] = __cosf(a2[0].x); C[1] = __cosf(a2[0].y);
        C[2] = __cosf(a2[1].x); C[3] = __cosf(a2[1].y);
        C[4] = __cosf(a2[2].x); C[5] = __cosf(a2[2].y);

        // tree-structured products (depth 3)
        float p01 = C[0]*C[1], p23 = C[2]*C[3], p45 = C[4]*C[5];
        float z[6];
        z[1] = p01;
        z[2] = p01*C[2];
        z[3] = p01*p23;
        z[4] = z[3]*C[4];
        z[5] = z[3]*p45;
        z[0] = C[1]*(p23*p45);

        float act[6];
        #pragma unroll
        for (int w = 0; w < 6; ++w) {
            float y   = z[w]*z[w];
            float num = fmaf(y, fmaf(y, n2, n1), n0);
            float den = fmaf(y, d1, d0);
            act[w] = fmaf(z[w]*num, fast_rcp(den), c0);
        }

        // quad-broadcast exchange via DPP: all four gates' act[6] to every lane
        float F[6], I[6], U[6], O[6];
        #pragma unroll
        for (int w = 0; w < 6; ++w) {
            F[w] = quad_bcast<0>(act[w]);
            I[w] = quad_bcast<1>(act[w]);
            U[w] = quad_bcast<2>(act[w]);
            O[w] = quad_bcast<3>(act[w]);
        }

        #pragma unroll
        for (int w = 0; w < 6; ++w) {
            c[w] = fmaf(F[w], c[w], I[w]*U[w]);
            // tanh(c) via Pade(5,4): c*(945+105y+y^2)/(945+420y+15y^2)
            float y   = c[w]*c[w];
            float num = fmaf(y, fmaf(y, 1.f, 105.f), 945.f);
            float den = fmaf(y, fmaf(y, 15.f, 420.f), 945.f);
            float tc  = c[w]*num*fast_rcp(den);
            h[w] = O[w]*tc;
        }

        if (g < 3) {
            float2 v;
            v.x = (g==0) ? h[0] : (g==1) ? h[2] : h[4];
            v.y = (g==0) ? h[1] : (g==1) ? h[3] : h[5];
            *(float2*)(out + (t*256 + b)*6 + g*2) = v;
        }
    }

    if (g < 3) {
        float2 v;
        v.x = (g==0) ? h[0] : (g==1) ? h[2] : h[4];
        v.y = (g==0) ? h[1] : (g==1) ? h[3] : h[5];
        *(float2*)(out + 64*256*6 + b*6 + g*2) = v;
        float2 u;
        u.x = (g==0) ? c[0] : (g==1) ? c[2] : c[4];
        u.y = (g==0) ? c[1] : (g==1) ? c[3] : c[5];
        *(float2*)(out + 64*256*6 + 256*6 + b*6 + g*2) = u;
    }
}

extern "C" void kernel_launch(void* const* d_in, const int* in_sizes, int n_in,
                              void* d_out, int out_size, void* d_ws, size_t ws_size,
                              hipStream_t stream) {
    const float* X   = (const float*)d_in[0];
    const float* Wf  = (const float*)d_in[1];
    const float* bf_ = (const float*)d_in[2];
    const float* Wi  = (const float*)d_in[3];
    const float* bi_ = (const float*)d_in[4];
    const float* Wu  = (const float*)d_in[5];
    const float* bu_ = (const float*)d_in[6];
    const float* Wo  = (const float*)d_in[7];
    const float* bo_ = (const float*)d_in[8];
    const float* thf = (const float*)d_in[9];
    const float* thi = (const float*)d_in[10];
    const float* thu = (const float*)d_in[11];
    const float* tho = (const float*)d_in[12];

    float* pre = (float*)d_ws;           // 16384*24 floats = 1.57 MB
    float* out = (float*)d_out;

    gemm_pre<<<512, 512, 0, stream>>>(X, Wf, bf_, Wi, bi_, Wu, bu_, Wo, bo_,
                                      thf, thi, thu, tho, pre);
    qlstm_scan<<<16, 64, 0, stream>>>(pre, Wf, Wi, Wu, Wo, out);
}

// Round 9
// 137.607 us; speedup vs baseline: 1.0531x; 1.0138x over previous
//
#include <hip/hip_runtime.h>

// QLSTM: T=64, B=256, D=512, NQ=6.
// Closed form for _qlayer: with C_w = cos(x_w + theta_w):
//   z0 = C1*C2*C3*C4*C5, z1 = C0*C1, z2 = C0*C1*C2, z3 = C0..C3, z4 = C0..C4, z5 = C0..C5
//
// gemm_pre (R9): occupancy fix. Cross-round anchors (R2/R4: fixed+scan =
//   113.7 us) show gemm was ~26 us across R5-R8 -- VMEM-latency bound at
//   8 waves/CU (acc=96 VGPR -> over the 128 cliff). R9: wave tile = 4 rows
//   x 12 cols (acc=48), grid 1024x512, __launch_bounds__(512,4) caps VGPR
//   at 128 -> 16 waves/CU, 2 blocks/CU co-resident -> 2x latency hiding.
//   - k across lanes; A reads coalesced global dwords, 1-chunk register
//     prefetch, no barriers in k-loop.
//   - W staged once per block into LDS stride-25 (odd stride -> all 32
//     banks, conflict-free); pair reads (c, c+6) -> ds_read2_b32.
//   - quad DPP reduce, static register indexing ONLY (R4 lesson: dynamic
//     reg indexing -> scratch spill, 845 MB traffic).
// qlstm_scan (unchanged from R8): 4 thr/batch, DPP quad_perm exchange,
//   2-deep prefetch, pk_fma h@Wh, polynomial activations (no v_exp).

typedef float v2f __attribute__((ext_vector_type(2)));

__device__ __forceinline__ float fast_rcp(float x) { return __builtin_amdgcn_rcpf(x); }

template <int CTRL>
__device__ __forceinline__ float dpp_add(float x) {
    int t = __builtin_amdgcn_mov_dpp(__float_as_int(x), CTRL, 0xF, 0xF, true);
    return x + __int_as_float(t);
}

template <int G>
__device__ __forceinline__ float quad_bcast(float v) {
    int i = __builtin_amdgcn_mov_dpp(__float_as_int(v), G * 0x55, 0xF, 0xF, true);
    return __int_as_float(i);
}

__global__ __launch_bounds__(512, 4) void gemm_pre(
    const float* __restrict__ X,
    const float* __restrict__ Wf, const float* __restrict__ bf,
    const float* __restrict__ Wi, const float* __restrict__ bi,
    const float* __restrict__ Wu, const float* __restrict__ bu,
    const float* __restrict__ Wo, const float* __restrict__ bo,
    const float* __restrict__ thf, const float* __restrict__ thi,
    const float* __restrict__ thu, const float* __restrict__ tho,
    float* __restrict__ pre)
{
    // W_lds[k*25 + c] = col c of row k (c = g*6+j); 512*25 = 12800 floats.
    // Epilogue overlays red[(w*48+v)*16+q], 6144 floats.
    __shared__ float W_lds[12800];

    const int tid  = threadIdx.x;
    const int w    = tid >> 6;          // wave 0..7
    const int lane = tid & 63;
    const int rg   = w >> 1;            // row group 0..3 (4 rows each)
    const int cg   = w & 1;             // col half 0..1 (12 cols each)
    const int rowbase = blockIdx.x * 16;

    // ---- stage W into LDS (once per block); thread tid stages row k=tid ----
    {
        const int k = tid;
        #pragma unroll
        for (int g = 0; g < 4; ++g) {
            const float* Wp = (g==0)?Wf:(g==1)?Wi:(g==2)?Wu:Wo;
            const float2* s = (const float2*)(Wp + k*6);
            float2 s0 = s[0], s1 = s[1], s2 = s[2];
            float* d = W_lds + k*25 + g*6;
            d[0] = s0.x; d[1] = s0.y; d[2] = s1.x;
            d[3] = s1.y; d[4] = s2.x; d[5] = s2.y;
        }
    }
    __syncthreads();

    // ---- main loop: 8 chunks of 64 k, register prefetch of A ----
    v2f acc[4][6];                      // acc[r][p] = {col cg*12+p, col cg*12+p+6}
    #pragma unroll
    for (int r = 0; r < 4; ++r)
        #pragma unroll
        for (int p = 0; p < 6; ++p) acc[r][p] = (v2f){0.f, 0.f};

    const float* Xr0 = X + (rowbase + rg*4)*512 + lane;
    const int colbase = cg*12;

    float pa[4];
    #pragma unroll
    for (int r = 0; r < 4; ++r) pa[r] = Xr0[r*512];

    #pragma unroll
    for (int kb = 0; kb < 512; kb += 64) {
        const float* Wrow = W_lds + (kb + lane)*25 + colbase;
        float a0 = pa[0], a1 = pa[1], a2 = pa[2], a3 = pa[3];
        if (kb < 448) {
            #pragma unroll
            for (int r = 0; r < 4; ++r) pa[r] = Xr0[kb + 64 + r*512];
        }
        #pragma unroll
        for (int p = 0; p < 6; ++p) {
            float wa = Wrow[p];
            float wb = Wrow[p + 6];     // merges into ds_read2_b32, conflict-free
            v2f wv = (v2f){wa, wb};
            acc[0][p] = __builtin_elementwise_fma((v2f){a0,a0}, wv, acc[0][p]);
            acc[1][p] = __builtin_elementwise_fma((v2f){a1,a1}, wv, acc[1][p]);
            acc[2][p] = __builtin_elementwise_fma((v2f){a2,a2}, wv, acc[2][p]);
            acc[3][p] = __builtin_elementwise_fma((v2f){a3,a3}, wv, acc[3][p]);
        }
    }

    // ---- quad reduction: static indexing only ----
    #pragma unroll
    for (int r = 0; r < 4; ++r)
        #pragma unroll
        for (int p = 0; p < 6; ++p) {
            float x = acc[r][p].x;
            x = dpp_add<0xB1>(x);       // quad_perm [1,0,3,2]
            x = dpp_add<0x4E>(x);       // quad_perm [2,3,0,1]
            acc[r][p].x = x;
            float y = acc[r][p].y;
            y = dpp_add<0xB1>(y);
            y = dpp_add<0x4E>(y);
            acc[r][p].y = y;
        }

    // flat v = r*12 + ph, ph = p + 6*e  ->  acc[v/12][v%6].{x if ph<6 else y}
    #define ACCV(v) ((((v) % 12) < 6) ? acc[(v)/12][(v)%6].x \
                                      : acc[(v)/12][(v)%6].y)
    const int j = lane & 3;             // which of the 4 values this lane stores
    const int q = lane >> 2;            // quad index 0..15
    const bool j1 = (j & 1) != 0, j2 = (j & 2) != 0;
    float sel[12];
    #pragma unroll
    for (int i = 0; i < 12; ++i) {
        float c0 = ACCV(i*4 + 0), c1 = ACCV(i*4 + 1);
        float c2 = ACCV(i*4 + 2), c3 = ACCV(i*4 + 3);
        float lo = j1 ? c1 : c0;
        float hi = j1 ? c3 : c2;
        sel[i] = j2 ? hi : lo;
    }
    #undef ACCV

    __syncthreads();                    // everyone done reading W_lds
    #pragma unroll
    for (int i = 0; i < 12; ++i) {
        // addr = (w*48 + i*4 + j)*16 + q : lanes cover 64 consecutive dwords
        W_lds[(w*48 + i*4 + j)*16 + q] = sel[i];
    }
    __syncthreads();

    // ---- final: 384 outputs per block (8 waves * 4 rows * 12 cols) ----
    if (tid < 384) {
        int o = tid;
        int ww = o / 48, v = o - ww*48;
        int rr = v / 12, ph = v - rr*12;
        const float4* rp = (const float4*)(W_lds + (ww*48 + v)*16);
        float4 r0 = rp[0], r1 = rp[1], r2 = rp[2], r3 = rp[3];
        float s = ((r0.x+r0.y)+(r0.z+r0.w)) + ((r1.x+r1.y)+(r1.z+r1.w))
                + ((r2.x+r2.y)+(r2.z+r2.w)) + ((r3.x+r3.y)+(r3.z+r3.w));
        int col = (ww & 1)*12 + ph;
        int g = col / 6, jg = col - g*6;
        const float* bb = (g==0)?bf:(g==1)?bi:(g==2)?bu:bo;
        const float* tt = (g==0)?thf:(g==1)?thi:(g==2)?thu:tho;
        s += bb[jg] + tt[jg];
        int row = rowbase + (ww >> 1)*4 + rr;
        pre[row*24 + col] = s;
    }
}

__global__ __launch_bounds__(64, 1) void qlstm_scan(
    const float* __restrict__ pre,
    const float* __restrict__ Wf, const float* __restrict__ Wi,
    const float* __restrict__ Wu, const float* __restrict__ Wo,
    float* __restrict__ out)
{
    // 4 threads per batch element (one per gate), one aligned hw quad per batch.
    const int lane = threadIdx.x;
    const int bl   = lane >> 2;          // batch-local 0..15
    const int g    = lane & 3;           // 0=f 1=i 2=u 3=o
    const int b    = blockIdx.x * 16 + bl;

    // this gate's recurrent weights, packed as v2f pairs (rows 512..517 of Wg)
    const float* Wg = (g==0)?Wf:(g==1)?Wi:(g==2)?Wu:Wo;
    v2f Wh2[6][3];
    #pragma unroll
    for (int j = 0; j < 6; ++j)
        #pragma unroll
        for (int p = 0; p < 3; ++p)
            Wh2[j][p] = (v2f){Wg[(512 + j)*6 + 2*p], Wg[(512 + j)*6 + 2*p + 1]};

    // act(z) = c0 + z*(n0 + n1*y + n2*y^2) * rcp(d0 + d1*y), y = z^2, z in [-1,1]
    // sigmoid (g!=2): 0.5 + z/4 - z^3/48 + z^5/480   (err <= 2.1e-4)
    // tanh    (g==2): z*(15+y)/(15+6y)  Pade(3,2)    (err <= 3e-4)
    const float c0 = (g==2) ? 0.f        : 0.5f;
    const float n0 = (g==2) ? 15.f       : 0.25f;
    const float n1 = (g==2) ? 1.f        : -0.020833333f;
    const float n2 = (g==2) ? 0.f        : 0.0020833333f;
    const float d0 = (g==2) ? 15.f       : 1.f;
    const float d1 = (g==2) ? 6.f        : 0.f;

    float h[6], c[6];
    #pragma unroll
    for (int w = 0; w < 6; ++w) { h[w] = 0.f; c[w] = 0.f; }

    // 2-step-deep prefetch of pre
    const float* pb = pre + b*24 + g*6;
    v2f x0 = *(const v2f*)(pb);
    v2f x1 = *(const v2f*)(pb + 2);
    v2f x2 = *(const v2f*)(pb + 4);
    v2f n0v = *(const v2f*)(pb + 256*24);
    v2f n1v = *(const v2f*)(pb + 256*24 + 2);
    v2f n2v = *(const v2f*)(pb + 256*24 + 4);

    for (int t = 0; t < 64; ++t) {
        v2f a2[3] = {x0, x1, x2};
        x0 = n0v; x1 = n1v; x2 = n2v;
        int tn = (t < 62) ? (t + 2) : 63;   // prefetch t+2
        const float* pn = pre + (tn*256 + b)*24 + g*6;
        n0v = *(const v2f*)(pn);
        n1v = *(const v2f*)(pn + 2);
        n2v = *(const v2f*)(pn + 4);

        // a = xw + h@Wh via packed fma (18 v_pk_fma_f32)
        #pragma unroll
        for (int j = 0; j < 6; ++j) {
            v2f hj = (v2f){h[j], h[j]};
            #pragma unroll
            for (int p = 0; p < 3; ++p)
                a2[p] = __builtin_elementwise_fma(hj, Wh2[j][p], a2[p]);
        }

        float C[6];
        C[0] = __cosf(a2[0].x); C[1] = __cosf(a2[0].y);
        C[2] = __cosf(a2[1].x); C[3] = __cosf(a2[1].y);
        C[4] = __cosf(a2[2].x); C[5] = __cosf(a2[2].y);

        // tree-structured products (depth 3)
        float p01 = C[0]*C[1], p23 = C[2]*C[3], p45 = C[4]*C[5];
        float z[6];
        z[1] = p01;
        z[2] = p01*C[2];
        z[3] = p01*p23;
        z[4] = z[3]*C[4];
        z[5] = z[3]*p45;
        z[0] = C[1]*(p23*p45);

        float act[6];
        #pragma unroll
        for (int w = 0; w < 6; ++w) {
            float y   = z[w]*z[w];
            float num = fmaf(y, fmaf(y, n2, n1), n0);
            float den = fmaf(y, d1, d0);
            act[w] = fmaf(z[w]*num, fast_rcp(den), c0);
        }

        // quad-broadcast exchange via DPP: all four gates' act[6] to every lane
        float F[6], I[6], U[6], O[6];
        #pragma unroll
        for (int w = 0; w < 6; ++w) {
            F[w] = quad_bcast<0>(act[w]);
            I[w] = quad_bcast<1>(act[w]);
            U[w] = quad_bcast<2>(act[w]);
            O[w] = quad_bcast<3>(act[w]);
        }

        #pragma unroll
        for (int w = 0; w < 6; ++w) {
            c[w] = fmaf(F[w], c[w], I[w]*U[w]);
            // tanh(c) via Pade(5,4): c*(945+105y+y^2)/(945+420y+15y^2)
            float y   = c[w]*c[w];
            float num = fmaf(y, fmaf(y, 1.f, 105.f), 945.f);
            float den = fmaf(y, fmaf(y, 15.f, 420.f), 945.f);
            float tc  = c[w]*num*fast_rcp(den);
            h[w] = O[w]*tc;
        }

        if (g < 3) {
            float2 v;
            v.x = (g==0) ? h[0] : (g==1) ? h[2] : h[4];
            v.y = (g==0) ? h[1] : (g==1) ? h[3] : h[5];
            *(float2*)(out + (t*256 + b)*6 + g*2) = v;
        }
    }

    if (g < 3) {
        float2 v;
        v.x = (g==0) ? h[0] : (g==1) ? h[2] : h[4];
        v.y = (g==0) ? h[1] : (g==1) ? h[3] : h[5];
        *(float2*)(out + 64*256*6 + b*6 + g*2) = v;
        float2 u;
        u.x = (g==0) ? c[0] : (g==1) ? c[2] : c[4];
        u.y = (g==0) ? c[1] : (g==1) ? c[3] : c[5];
        *(float2*)(out + 64*256*6 + 256*6 + b*6 + g*2) = u;
    }
}

extern "C" void kernel_launch(void* const* d_in, const int* in_sizes, int n_in,
                              void* d_out, int out_size, void* d_ws, size_t ws_size,
                              hipStream_t stream) {
    const float* X   = (const float*)d_in[0];
    const float* Wf  = (const float*)d_in[1];
    const float* bf_ = (const float*)d_in[2];
    const float* Wi  = (const float*)d_in[3];
    const float* bi_ = (const float*)d_in[4];
    const float* Wu  = (const float*)d_in[5];
    const float* bu_ = (const float*)d_in[6];
    const float* Wo  = (const float*)d_in[7];
    const float* bo_ = (const float*)d_in[8];
    const float* thf = (const float*)d_in[9];
    const float* thi = (const float*)d_in[10];
    const float* thu = (const float*)d_in[11];
    const float* tho = (const float*)d_in[12];

    float* pre = (float*)d_ws;           // 16384*24 floats = 1.57 MB
    float* out = (float*)d_out;

    gemm_pre<<<1024, 512, 0, stream>>>(X, Wf, bf_, Wi, bi_, Wu, bu_, Wo, bo_,
                                       thf, thi, thu, tho, pre);
    qlstm_scan<<<16, 64, 0, stream>>>(pre, Wf, Wi, Wu, Wo, out);
}